// Round 7
// baseline (377.723 us; speedup 1.0000x reference)
//
#include <hip/hip_runtime.h>

typedef unsigned short u16;
typedef __attribute__((ext_vector_type(8))) short bf16x8_t;
typedef __attribute__((ext_vector_type(4))) float f32x4_t;

__device__ __forceinline__ u16 f2bf(float x){
  union { float f; unsigned u; } v; v.f = x;
  unsigned r = v.u + 0x7FFFu + ((v.u >> 16) & 1u);
  return (u16)(r >> 16);
}
__device__ __forceinline__ float bf2f(u16 h){
  union { unsigned u; float f; } v; v.u = ((unsigned)h) << 16;
  return v.f;
}
__device__ __forceinline__ u16 hi16(float x){
  union { float f; unsigned u; } v; v.f = x;
  return (u16)(v.u >> 16);          // truncation: bias cancels in renormalization
}

// async global->LDS DMA, 16B/lane; data lands at base + lane*16.
__device__ __forceinline__ void gl2lds16(const u16* g, u16* l){
  __builtin_amdgcn_global_load_lds((const __attribute__((address_space(1))) void*)g,
                                   (__attribute__((address_space(3))) void*)l, 16, 0, 0);
}

// ---- prep: one launch.
// blocks 0..8191   : X=[gene|expr] hi/lo split
// blocks 8192..8319: Wv (64) / Wo (64) transpose -> bf16-hi B^T
// blocks 8320..8575: combined weights Wfq^T = (Wf@Wq)^T, Wfk^T (f32 acc -> bf16 hi)
//                    + combined biases bfq = bf@Wq + bq, bfk (kx==0 blocks)
__global__ __launch_bounds__(256) void prep_kernel(
    const float* __restrict__ gene, const float* __restrict__ expr,
    const float* __restrict__ Wf, const float* __restrict__ Wq,
    const float* __restrict__ Wk, const float* __restrict__ Wv,
    const float* __restrict__ Wo,
    const float* __restrict__ bfv, const float* __restrict__ bq, const float* __restrict__ bk,
    u16* __restrict__ Xh, u16* __restrict__ Xl,
    u16* __restrict__ Wfqt, u16* __restrict__ Wfkt,
    u16* __restrict__ Wvth, u16* __restrict__ Woth,
    float* __restrict__ bfq, float* __restrict__ bfk)
{
  int tid = threadIdx.x;
  if (blockIdx.x < 8192){
    size_t e = ((size_t)blockIdx.x * 256 + tid) * 4;
    int row = (int)(e >> 10);
    int col = (int)(e & 1023);
    const float* src = (col < 512) ? (gene + (size_t)row * 512 + col)
                                   : (expr + (size_t)row * 512 + (col - 512));
    float4 v = *(const float4*)src;
    float a[4] = {v.x, v.y, v.z, v.w};
    u16 hs[4], ls[4];
#pragma unroll
    for (int i = 0; i < 4; i++){
      hs[i] = f2bf(a[i]);
      ls[i] = f2bf(a[i] - bf2f(hs[i]));
    }
    *(uint2*)(Xh + e) = make_uint2(hs[0] | ((unsigned)hs[1] << 16), hs[2] | ((unsigned)hs[3] << 16));
    *(uint2*)(Xl + e) = make_uint2(ls[0] | ((unsigned)ls[1] << 16), ls[2] | ((unsigned)ls[3] << 16));
    return;
  }
  int id = blockIdx.x - 8192;
  if (id < 128){
    // transpose W [512][512] f32 -> Wt [512][512] bf16 hi
    __shared__ float t[64][65];
    const float* W = (id < 64) ? Wv : Wo;
    u16* Th = (id < 64) ? Wvth : Woth;
    int tt = id & 63;
    int k0 = (tt >> 3) * 64, n0 = (tt & 7) * 64;
    int r = tid >> 4;
    int c4 = (tid & 15) * 4;
#pragma unroll
    for (int p = 0; p < 4; p++){
      int k = p * 16 + r;
      float4 v = *(const float4*)(W + (size_t)(k0 + k) * 512 + n0 + c4);
      t[c4 + 0][k] = v.x; t[c4 + 1][k] = v.y; t[c4 + 2][k] = v.z; t[c4 + 3][k] = v.w;
    }
    __syncthreads();
#pragma unroll
    for (int p = 0; p < 4; p++){
      int n = p * 16 + r;
      u16 hs[4];
#pragma unroll
      for (int i = 0; i < 4; i++) hs[i] = f2bf(t[n][c4 + i]);
      size_t o = (size_t)(n0 + n) * 512 + k0 + c4;
      *(uint2*)(Th + o) = make_uint2(hs[0] | ((unsigned)hs[1] << 16), hs[2] | ((unsigned)hs[3] << 16));
    }
    return;
  }
  id -= 128;                       // 0..255
  int mat = id >> 7;               // 0 = Q, 1 = K
  int t2 = id & 127;
  int kx = t2 >> 3, ny = t2 & 7;   // k-tile (of 1024), n-tile (of 512)
  const float* Wsec = mat ? Wk : Wq;
  u16* Outp = mat ? Wfkt : Wfqt;
  float* bout = mat ? bfk : bfq;
  const float* bsec = mat ? bk : bq;
  int k0 = kx * 64, n0 = ny * 64;
  __shared__ float sF[32][65];     // [j][k]  Wf[k0+k][jc+j]
  __shared__ float sQm[32][65];    // [j][n]  Wsec[jc+j][n0+n]
  float acc[4][4];                 // [kk][nn]
#pragma unroll
  for (int i = 0; i < 4; i++)
#pragma unroll
    for (int j = 0; j < 4; j++) acc[i][j] = 0.f;
  int tn = tid & 15, tk = tid >> 4;
  for (int jc = 0; jc < 512; jc += 32){
    __syncthreads();
    {
      int k = tid >> 2;
      int j0 = (tid & 3) * 8;
      float4 v0 = *(const float4*)(Wf + (size_t)(k0 + k) * 512 + jc + j0);
      float4 v1 = *(const float4*)(Wf + (size_t)(k0 + k) * 512 + jc + j0 + 4);
      sF[j0 + 0][k] = v0.x; sF[j0 + 1][k] = v0.y; sF[j0 + 2][k] = v0.z; sF[j0 + 3][k] = v0.w;
      sF[j0 + 4][k] = v1.x; sF[j0 + 5][k] = v1.y; sF[j0 + 6][k] = v1.z; sF[j0 + 7][k] = v1.w;
    }
    {
      int j = tid >> 3;
      int n8 = (tid & 7) * 8;
      float4 v0 = *(const float4*)(Wsec + (size_t)(jc + j) * 512 + n0 + n8);
      float4 v1 = *(const float4*)(Wsec + (size_t)(jc + j) * 512 + n0 + n8 + 4);
      sQm[j][n8 + 0] = v0.x; sQm[j][n8 + 1] = v0.y; sQm[j][n8 + 2] = v0.z; sQm[j][n8 + 3] = v0.w;
      sQm[j][n8 + 4] = v1.x; sQm[j][n8 + 5] = v1.y; sQm[j][n8 + 6] = v1.z; sQm[j][n8 + 7] = v1.w;
    }
    __syncthreads();
#pragma unroll 8
    for (int j = 0; j < 32; j++){
      float a[4], bb[4];
#pragma unroll
      for (int i = 0; i < 4; i++){ a[i] = sQm[j][tn * 4 + i]; bb[i] = sF[j][tk * 4 + i]; }
#pragma unroll
      for (int kk = 0; kk < 4; kk++)
#pragma unroll
        for (int nn = 0; nn < 4; nn++) acc[kk][nn] += bb[kk] * a[nn];
    }
  }
#pragma unroll
  for (int nn = 0; nn < 4; nn++)
#pragma unroll
    for (int kk = 0; kk < 4; kk++)
      Outp[(size_t)(n0 + tn * 4 + nn) * 1024 + k0 + tk * 4 + kk] = f2bf(acc[kk][nn]);
  if (kx == 0 && tid < 64){
    float s = 0.f;
    for (int j = 0; j < 512; j++) s += bfv[j] * Wsec[(size_t)j * 512 + n0 + tid];
    bout[n0 + tid] = s + bsec[n0 + tid];
  }
}

// ---- double-buffered GEMM core: BM=128 BN=64, template BK ----
// ONE barrier per BK-iter: sync -> issue DMA for tile i+1 (alt buffer) ->
// compute tile i. SPLITS: 2 = aH*bH+aL*bH ; 1 = aH*bH
template<int SPLITS, int BK>
__device__ __forceinline__ void gemm_core_db(
    const u16* __restrict__ Ah, const u16* __restrict__ Al, int lda,
    const u16* __restrict__ Bh, int K,
    int m0, int n0, f32x4_t (&acc)[4][2],
    u16* sAh, u16* sAl, u16* sBh)
{
  constexpr int NH  = BK / 32;
  constexpr int ASZ = 128 * BK;
  constexpr int BSZ = 64 * BK;
  int tid = threadIdx.x;
  int lane = tid & 63, w = tid >> 6, quad = lane >> 4, l15 = lane & 15;
  int wm = w & 1, wn = w >> 1;
  int lrow = lane >> 2;
  int swzS = ((lane >> 2) & 3) ^ ((lane >> 4) & 3);
  int gkq  = ((lane & 3) ^ swzS) * 8;
  const u16* pA0 = Ah + (size_t)(m0 + w * 32 + lrow) * lda + gkq;
  const u16* pA1 = Ah + (size_t)(m0 + w * 32 + 16 + lrow) * lda + gkq;
  const u16* pL0 = (SPLITS >= 2) ? Al + (size_t)(m0 + w * 32 + lrow) * lda + gkq : nullptr;
  const u16* pL1 = (SPLITS >= 2) ? Al + (size_t)(m0 + w * 32 + 16 + lrow) * lda + gkq : nullptr;
  const u16* pB0 = Bh + (size_t)(n0 + w * 16 + lrow) * K + gkq;
  int pq = (quad ^ ((l15 & 3) ^ ((l15 >> 2) & 3))) * 8;
  const int NIT = K / BK;

  auto stage = [&](int it){
    int bi = it & 1, k0 = it * BK;
    u16* dA = sAh + bi * ASZ + w * 1024;
    u16* dB = sBh + bi * BSZ + w * 512;
#pragma unroll
    for (int hf = 0; hf < NH; hf++){
      gl2lds16(pA0 + k0 + hf * 32, dA + hf * 4096);
      gl2lds16(pA1 + k0 + hf * 32, dA + hf * 4096 + 512);
      if constexpr (SPLITS >= 2){
        u16* dAl = sAl + bi * ASZ + w * 1024;
        gl2lds16(pL0 + k0 + hf * 32, dAl + hf * 4096);
        gl2lds16(pL1 + k0 + hf * 32, dAl + hf * 4096 + 512);
      }
      gl2lds16(pB0 + k0 + hf * 32, dB + hf * 2048);
    }
  };

  stage(0);
  for (int it = 0; it < NIT; ++it){
    int bi = it & 1;
    __syncthreads();                 // drains tile-i DMA (issued one iter ago)
    if (it + 1 < NIT) stage(it + 1);
#pragma unroll
    for (int hf = 0; hf < NH; hf++){
      bf16x8_t aH[4], aL[4], bH[2];
#pragma unroll
      for (int mi = 0; mi < 4; mi++){
        int ad = (wm * 64 + mi * 16 + l15) * 32 + pq + bi * ASZ + hf * 4096;
        aH[mi] = *(const bf16x8_t*)&sAh[ad];
        if constexpr (SPLITS >= 2) aL[mi] = *(const bf16x8_t*)&sAl[ad];
      }
#pragma unroll
      for (int ni = 0; ni < 2; ni++){
        int bd = (wn * 32 + ni * 16 + l15) * 32 + pq + bi * BSZ + hf * 2048;
        bH[ni] = *(const bf16x8_t*)&sBh[bd];
      }
#pragma unroll
      for (int mi = 0; mi < 4; mi++)
#pragma unroll
        for (int ni = 0; ni < 2; ni++){
          acc[mi][ni] = __builtin_amdgcn_mfma_f32_16x16x32_bf16(aH[mi], bH[ni], acc[mi][ni], 0, 0, 0);
          if constexpr (SPLITS >= 2)
            acc[mi][ni] = __builtin_amdgcn_mfma_f32_16x16x32_bf16(aL[mi], bH[ni], acc[mi][ni], 0, 0, 0);
        }
    }
  }
}

// Q|K|V in one launch. grid (64, 24): side = y>>3 (0=Q,1=K,2=V), n0=(y&7)*64.
// Q,K: A = full X (lda 1024, K=1024), B = combined Wfq^T/Wfk^T.
// V:   A = expr half (lda 1024, K=512), B = Wv^T.
// 40 KB live LDS + 12 KB pad -> exactly 3 blocks/CU (grid 1536 = 3/CU exact).
__global__ __launch_bounds__(256, 3) void gemm_qkv_kernel(
    const u16* __restrict__ Xh, const u16* __restrict__ Xl,
    const u16* __restrict__ Wfqt, const u16* __restrict__ Wfkt, const u16* __restrict__ Wvth,
    const float* __restrict__ bfq, const float* __restrict__ bfk, const float* __restrict__ bv,
    u16* __restrict__ Q, u16* __restrict__ Kout, u16* __restrict__ Vt, float qsc)
{
  __shared__ __align__(16) u16 sAh[2 * 4096], sAl[2 * 4096], sBh[2 * 2048];
  __shared__ u16 sPad[6144];   // occupancy shaper: 53248 B -> 3 blocks/CU
  if (qsc < 0.f){ sPad[threadIdx.x] = 0; __syncthreads(); sAh[0] = sPad[0]; }

  int side = blockIdx.y >> 3;
  int m0 = blockIdx.x * 128, n0 = (blockIdx.y & 7) * 64;
  const u16* Ah = (side == 2) ? Xh + 512 : Xh;
  const u16* Al = (side == 2) ? Xl + 512 : Xl;
  int K = (side == 2) ? 512 : 1024;
  const u16* Bh = (side == 0) ? Wfqt : (side == 1) ? Wfkt : Wvth;
  const float* bias = (side == 0) ? bfq : (side == 1) ? bfk : bv;

  f32x4_t acc[4][2];
#pragma unroll
  for (int i = 0; i < 4; i++)
#pragma unroll
    for (int j = 0; j < 2; j++)
#pragma unroll
      for (int r = 0; r < 4; r++) acc[i][j][r] = 0.f;
  gemm_core_db<2, 32>(Ah, Al, 1024, Bh, K, m0, n0, acc, sAh, sAl, sBh);

  int lane = threadIdx.x & 63, w = threadIdx.x >> 6, quad = lane >> 4, l15 = lane & 15;
  int wm = w & 1, wn = w >> 1;
#pragma unroll
  for (int mi = 0; mi < 4; mi++)
#pragma unroll
    for (int ni = 0; ni < 2; ni++){
      int gn = n0 + wn * 32 + ni * 16 + l15;
      float bs = bias[gn];
      int gm0 = m0 + wm * 64 + mi * 16 + quad * 4;
#pragma unroll
      for (int r = 0; r < 4; r++){
        float v = acc[mi][ni][r] + bs;
        int gm = gm0 + r;
        if (side == 0){
          Q[(size_t)gm * 512 + gn] = f2bf(v * qsc);
        } else if (side == 1){
          Kout[(size_t)gm * 512 + gn] = f2bf(v);
        } else {
          int bb = gm >> 11, s = gm & 2047;
          int hh = gn >> 6, d = gn & 63;
          Vt[((size_t)((bb * 8 + hh) * 64 + d) << 11) + s] = f2bf(v);
        }
      }
    }
}

// out = O @ Wo + bo -> f32. grid (64, 8). 48 KB -> 3/CU, 512 blocks all resident.
__global__ __launch_bounds__(256, 2) void gemm_o_kernel(
    const u16* __restrict__ Oh, const u16* __restrict__ Woth,
    const float* __restrict__ bias, float* __restrict__ out)
{
  __shared__ __align__(16) u16 sAh[2 * 8192], sBh[2 * 4096];
  int m0 = blockIdx.x * 128, n0 = blockIdx.y * 64;
  f32x4_t acc[4][2];
#pragma unroll
  for (int i = 0; i < 4; i++)
#pragma unroll
    for (int j = 0; j < 2; j++)
#pragma unroll
      for (int r = 0; r < 4; r++) acc[i][j][r] = 0.f;
  gemm_core_db<1, 64>(Oh, nullptr, 512, Woth, 512, m0, n0, acc, sAh, nullptr, sBh);

  int lane = threadIdx.x & 63, w = threadIdx.x >> 6, quad = lane >> 4, l15 = lane & 15;
  int wm = w & 1, wn = w >> 1;
#pragma unroll
  for (int mi = 0; mi < 4; mi++)
#pragma unroll
    for (int ni = 0; ni < 2; ni++){
      int gn = n0 + wn * 32 + ni * 16 + l15;
      float bs = bias[gn];
      int gm0 = m0 + wm * 64 + mi * 16 + quad * 4;
#pragma unroll
      for (int r = 0; r < 4; r++)
        out[(size_t)(gm0 + r) * 512 + gn] = acc[mi][ni][r] + bs;
    }
}

// ---- flash attention: 4 waves x 16 q = 64 q/block, double-buffered K/V,
// ONE barrier per iter, XOR-swizzled sP. LDS = 16K + 16K + 8K = 40960 B exactly
// -> 4 blocks/CU x 4 waves = 16 waves/CU = 4/SIMD (VGPR capped at 128).
// Q pre-scaled by 0.125*log2(e); p = M*exp2(s*M); l = sum p; O = (sum p*V)/l.
__global__ __launch_bounds__(256, 4) void flash_kernel(
    const u16* __restrict__ Qh, const u16* __restrict__ Kh,
    const u16* __restrict__ Vt, const float* __restrict__ Mm,
    u16* __restrict__ Oh)
{
  __shared__ __align__(16) u16 sKh[2 * 4096], sVt[2 * 4096], sP[4096];
  int tid = threadIdx.x, lane = tid & 63, w = tid >> 6, quad = lane >> 4, l15 = lane & 15;
  int bh = blockIdx.y, b = bh >> 3, h = bh & 7;
  int q0 = blockIdx.x * 64;

  int qrow = q0 + w * 16 + l15;
  const u16* qp = Qh + ((size_t)(b * 2048 + qrow)) * 512 + h * 64 + quad * 8;
  bf16x8_t qH[2];
  qH[0] = *(const bf16x8_t*)qp;  qH[1] = *(const bf16x8_t*)(qp + 32);

  float lp[4] = {0.f, 0.f, 0.f, 0.f};
  f32x4_t Oacc[4];
#pragma unroll
  for (int ni = 0; ni < 4; ni++)
#pragma unroll
    for (int r = 0; r < 4; r++) Oacc[ni][r] = 0.f;

  // staging: wave w stages rows [w*16, w*16+16); granule g holds cols (g^(row&7))*8..
  int srow = lane >> 3;
  int gc = ((lane & 7) ^ srow) * 8;
  const u16* gK = Kh + ((size_t)(b * 2048 + w * 16 + srow)) * 512 + h * 64 + gc;
  const u16* gV = Vt + ((size_t)(bh * 64 + w * 16 + srow)) * 2048 + gc;

  auto stage = [&](int it){
    int bi = it & 1, k0 = it * 64;
    u16* dK = sKh + bi * 4096 + w * 1024;
    u16* dV = sVt + bi * 4096 + w * 1024;
    gl2lds16(gK + (size_t)k0 * 512,       dK);
    gl2lds16(gK + (size_t)(k0 + 8) * 512, dK + 512);
    gl2lds16(gV + k0,                     dV);
    gl2lds16(gV + 8 * 2048 + k0,          dV + 512);
  };

  const float* Mbase = Mm + (size_t)b * 2048 * 2048 + (size_t)(q0 + w * 16) * 2048;
  stage(0);

  // M for tile 0
  float Mc[4][4];
#pragma unroll
  for (int ni = 0; ni < 4; ni++)
#pragma unroll
    for (int r = 0; r < 4; r++)
      Mc[ni][r] = Mbase[(size_t)(quad * 4 + r) * 2048 + ni * 16 + l15];

  int sw7 = l15 & 7;
  for (int it = 0; it < 32; ++it){
    int bi = it & 1;
    const u16* cK = sKh + bi * 4096;
    const u16* cV = sVt + bi * 4096;
    __syncthreads();                 // drains tile-i DMA (issued one iter ago)
    bool hasNext = (it + 1) < 32;
    if (hasNext) stage(it + 1);

    // prefetch next tile's M (consumed next iteration)
    float Mn[4][4];
    if (hasNext){
      int kn = (it + 1) * 64;
#pragma unroll
      for (int ni = 0; ni < 4; ni++)
#pragma unroll
        for (int r = 0; r < 4; r++)
          Mn[ni][r] = Mbase[(size_t)(quad * 4 + r) * 2048 + kn + ni * 16 + l15];
    }

    // scores = Q . K^T (bf16)
    f32x4_t S[4];
#pragma unroll
    for (int ni = 0; ni < 4; ni++)
#pragma unroll
      for (int r = 0; r < 4; r++) S[ni][r] = 0.f;
#pragma unroll
    for (int ni = 0; ni < 4; ni++){
      int kb = (ni * 16 + l15) * 64;
#pragma unroll
      for (int ds = 0; ds < 2; ds++){
        bf16x8_t kf = *(const bf16x8_t*)&cK[kb + (((ds * 4 + quad) ^ sw7)) * 8];
        S[ni] = __builtin_amdgcn_mfma_f32_16x16x32_bf16(qH[ds], kf, S[ni], 0, 0, 0);
      }
    }

    // p = M*exp2(s*M); per-lane l; truncation-store bf16 P (wave-private, swizzled)
#pragma unroll
    for (int ni = 0; ni < 4; ni++)
#pragma unroll
      for (int r = 0; r < 4; r++){
        float m = Mc[ni][r];
        float p = m * __builtin_amdgcn_exp2f(S[ni][r] * m);
        lp[r] += p;
        int row = quad * 4 + r;
        int colg = ni * 2 + (l15 >> 3);
        sP[w * 1024 + row * 64 + ((colg ^ (row & 7)) << 3) + (l15 & 7)] = hi16(p);
      }

    // O += P @ V (wave-private sP rows; lgkmcnt only, no barrier)
#pragma unroll
    for (int ds = 0; ds < 2; ds++){
      bf16x8_t pf = *(const bf16x8_t*)&sP[w * 1024 + l15 * 64 + (((ds * 4 + quad) ^ sw7) << 3)];
#pragma unroll
      for (int ni = 0; ni < 4; ni++){
        bf16x8_t vf = *(const bf16x8_t*)&cV[(ni * 16 + l15) * 64 + (((ds * 4 + quad) ^ sw7)) * 8];
        Oacc[ni] = __builtin_amdgcn_mfma_f32_16x16x32_bf16(pf, vf, Oacc[ni], 0, 0, 0);
      }
    }

    if (hasNext){
#pragma unroll
      for (int ni = 0; ni < 4; ni++)
#pragma unroll
        for (int r = 0; r < 4; r++) Mc[ni][r] = Mn[ni][r];
    }
  }

#pragma unroll
  for (int r = 0; r < 4; r++){
#pragma unroll
    for (int off = 1; off < 16; off <<= 1)
      lp[r] += __shfl_xor(lp[r], off);
  }

#pragma unroll
  for (int r = 0; r < 4; r++){
    float inv = 1.0f / lp[r];
    int q = q0 + w * 16 + quad * 4 + r;
    size_t rb = ((size_t)(b * 2048 + q)) * 512 + h * 64;
#pragma unroll
    for (int ni = 0; ni < 4; ni++)
      Oh[rb + ni * 16 + l15] = f2bf(Oacc[ni][r] * inv);
  }
}

extern "C" void kernel_launch(void* const* d_in, const int* in_sizes, int n_in,
                              void* d_out, int out_size, void* d_ws, size_t ws_size,
                              hipStream_t stream)
{
  const float* gene = (const float*)d_in[0];
  const float* expr = (const float*)d_in[1];
  const float* Mm   = (const float*)d_in[2];
  const float* Wf   = (const float*)d_in[3];
  const float* bfv  = (const float*)d_in[4];
  const float* Wq   = (const float*)d_in[5];
  const float* bq   = (const float*)d_in[6];
  const float* Wk   = (const float*)d_in[7];
  const float* bk   = (const float*)d_in[8];
  const float* Wv   = (const float*)d_in[9];
  const float* bv   = (const float*)d_in[10];
  const float* Wo   = (const float*)d_in[11];
  const float* bo   = (const float*)d_in[12];
  float* out = (float*)d_out;

  char* ws = (char*)d_ws;
  size_t off = 0;
  auto alloc = [&](size_t bytes) -> void* {
    void* p = (void*)(ws + off);
    off += (bytes + 255) & ~(size_t)255;
    return p;
  };
  u16* Xh    = (u16*)alloc(8192ull * 1024 * 2);
  u16* Xl    = (u16*)alloc(8192ull * 1024 * 2);
  u16* Wfqt  = (u16*)alloc(512ull * 1024 * 2);
  u16* Wfkt  = (u16*)alloc(512ull * 1024 * 2);
  u16* Wvth  = (u16*)alloc(512ull * 512 * 2);
  u16* Woth  = (u16*)alloc(512ull * 512 * 2);
  float* bfq = (float*)alloc(512 * 4);
  float* bfk = (float*)alloc(512 * 4);
  u16* Qh    = (u16*)alloc(8192ull * 512 * 2);
  u16* Kh    = (u16*)alloc(8192ull * 512 * 2);
  u16* Vt    = (u16*)alloc(8192ull * 512 * 2);
  u16* Oh = Xh;   // X dead after QKV; attention output aliases it

  const float QSC = 0.1803368801f;   // 0.125 * log2(e) — folded into Q, exp via exp2

  prep_kernel<<<8576, 256, 0, stream>>>(gene, expr, Wf, Wq, Wk, Wv, Wo, bfv, bq, bk,
                                        Xh, Xl, Wfqt, Wfkt, Wvth, Woth, bfq, bfk);
  gemm_qkv_kernel<<<dim3(64, 24), 256, 0, stream>>>(Xh, Xl, Wfqt, Wfkt, Wvth,
                                                    bfq, bfk, bv, Qh, Kh, Vt, QSC);
  flash_kernel<<<dim3(32, 32), 256, 0, stream>>>(Qh, Kh, Vt, Mm, Oh);
  gemm_o_kernel<<<dim3(64, 8), 256, 0, stream>>>(Oh, Woth, bo, out);

  (void)in_sizes; (void)n_in; (void)out_size; (void)ws_size;
}

// Round 8
// 330.575 us; speedup vs baseline: 1.1426x; 1.1426x over previous
//
#include <hip/hip_runtime.h>

typedef unsigned short u16;
typedef __attribute__((ext_vector_type(8))) short bf16x8_t;
typedef __attribute__((ext_vector_type(4))) float f32x4_t;

__device__ __forceinline__ u16 f2bf(float x){
  union { float f; unsigned u; } v; v.f = x;
  unsigned r = v.u + 0x7FFFu + ((v.u >> 16) & 1u);
  return (u16)(r >> 16);
}
__device__ __forceinline__ float bf2f(u16 h){
  union { unsigned u; float f; } v; v.u = ((unsigned)h) << 16;
  return v.f;
}
__device__ __forceinline__ u16 hi16(float x){
  union { float f; unsigned u; } v; v.f = x;
  return (u16)(v.u >> 16);          // truncation: bias cancels in renormalization
}

// async global->LDS DMA, 16B/lane; data lands at base + lane*16.
__device__ __forceinline__ void gl2lds16(const u16* g, u16* l){
  __builtin_amdgcn_global_load_lds((const __attribute__((address_space(1))) void*)g,
                                   (__attribute__((address_space(3))) void*)l, 16, 0, 0);
}

// ---- prep pass 1: all data-layout work, one launch, all streaming ----
// blocks 0..8191     : X=[gene|expr] hi/lo split
// +0..511 (id<512)   : Wf elementwise hi/lo split (row-major A operand)
// +512..575          : Wq^T split hi/lo     +576..639 : Wk^T split hi/lo
// +640..703          : Wv^T hi              +704..767 : Wo^T hi
// +768..771          : combined biases bfq = bf@Wq + bq, bfk = bf@Wk + bk
__global__ __launch_bounds__(256) void prep_kernel(
    const float* __restrict__ gene, const float* __restrict__ expr,
    const float* __restrict__ Wf, const float* __restrict__ Wq,
    const float* __restrict__ Wk, const float* __restrict__ Wv,
    const float* __restrict__ Wo,
    const float* __restrict__ bfv, const float* __restrict__ bq, const float* __restrict__ bk,
    u16* __restrict__ Xh, u16* __restrict__ Xl,
    u16* __restrict__ Wfh, u16* __restrict__ Wfl,
    u16* __restrict__ Wqth, u16* __restrict__ Wqtl,
    u16* __restrict__ Wkth, u16* __restrict__ Wktl,
    u16* __restrict__ Wvth, u16* __restrict__ Woth,
    float* __restrict__ bfq, float* __restrict__ bfk)
{
  int tid = threadIdx.x;
  if (blockIdx.x < 8192){
    size_t e = ((size_t)blockIdx.x * 256 + tid) * 4;
    int row = (int)(e >> 10);
    int col = (int)(e & 1023);
    const float* src = (col < 512) ? (gene + (size_t)row * 512 + col)
                                   : (expr + (size_t)row * 512 + (col - 512));
    float4 v = *(const float4*)src;
    float a[4] = {v.x, v.y, v.z, v.w};
    u16 hs[4], ls[4];
#pragma unroll
    for (int i = 0; i < 4; i++){
      hs[i] = f2bf(a[i]);
      ls[i] = f2bf(a[i] - bf2f(hs[i]));
    }
    *(uint2*)(Xh + e) = make_uint2(hs[0] | ((unsigned)hs[1] << 16), hs[2] | ((unsigned)hs[3] << 16));
    *(uint2*)(Xl + e) = make_uint2(ls[0] | ((unsigned)ls[1] << 16), ls[2] | ((unsigned)ls[3] << 16));
    return;
  }
  int id = blockIdx.x - 8192;
  if (id < 512){
    // Wf [1024][512] f32 -> hi/lo bf16, same layout (A operand of combine GEMM)
    size_t e = ((size_t)id * 1024 + (size_t)tid * 4);
    float4 v = *(const float4*)(Wf + e);
    float a[4] = {v.x, v.y, v.z, v.w};
    u16 hs[4], ls[4];
#pragma unroll
    for (int i = 0; i < 4; i++){
      hs[i] = f2bf(a[i]);
      ls[i] = f2bf(a[i] - bf2f(hs[i]));
    }
    *(uint2*)(Wfh + e) = make_uint2(hs[0] | ((unsigned)hs[1] << 16), hs[2] | ((unsigned)hs[3] << 16));
    *(uint2*)(Wfl + e) = make_uint2(ls[0] | ((unsigned)ls[1] << 16), ls[2] | ((unsigned)ls[3] << 16));
    return;
  }
  id -= 512;
  if (id < 256){
    // transpose W [512][512] f32 -> Wt [512][512] bf16 (hi, optional lo)
    __shared__ float t[64][65];
    int wi = id >> 6;                 // 0=Wq 1=Wk 2=Wv 3=Wo
    const float* W = (wi == 0) ? Wq : (wi == 1) ? Wk : (wi == 2) ? Wv : Wo;
    u16* Th = (wi == 0) ? Wqth : (wi == 1) ? Wkth : (wi == 2) ? Wvth : Woth;
    u16* Tl = (wi == 0) ? Wqtl : (wi == 1) ? Wktl : nullptr;
    int tt = id & 63;
    int k0 = (tt >> 3) * 64, n0 = (tt & 7) * 64;
    int r = tid >> 4;
    int c4 = (tid & 15) * 4;
#pragma unroll
    for (int p = 0; p < 4; p++){
      int k = p * 16 + r;
      float4 v = *(const float4*)(W + (size_t)(k0 + k) * 512 + n0 + c4);
      t[c4 + 0][k] = v.x; t[c4 + 1][k] = v.y; t[c4 + 2][k] = v.z; t[c4 + 3][k] = v.w;
    }
    __syncthreads();
#pragma unroll
    for (int p = 0; p < 4; p++){
      int n = p * 16 + r;
      u16 hs[4], ls[4];
#pragma unroll
      for (int i = 0; i < 4; i++){
        float x = t[n][c4 + i];
        hs[i] = f2bf(x);
        ls[i] = f2bf(x - bf2f(hs[i]));
      }
      size_t o = (size_t)(n0 + n) * 512 + k0 + c4;
      *(uint2*)(Th + o) = make_uint2(hs[0] | ((unsigned)hs[1] << 16), hs[2] | ((unsigned)hs[3] << 16));
      if (Tl)
        *(uint2*)(Tl + o) = make_uint2(ls[0] | ((unsigned)ls[1] << 16), ls[2] | ((unsigned)ls[3] << 16));
    }
    return;
  }
  id -= 256;                          // 0..3: combined biases
  int mat = id >> 1, half = id & 1;
  int n = half * 256 + tid;
  const float* Wsec = mat ? Wk : Wq;
  const float* bsec = mat ? bk : bq;
  float* bout = mat ? bfk : bfq;
  float s = 0.f;
  for (int j = 0; j < 512; j += 4){
    s += bfv[j]     * Wsec[(size_t)j * 512 + n];
    s += bfv[j + 1] * Wsec[(size_t)(j + 1) * 512 + n];
    s += bfv[j + 2] * Wsec[(size_t)(j + 2) * 512 + n];
    s += bfv[j + 3] * Wsec[(size_t)(j + 3) * 512 + n];
  }
  bout[n] = s + bsec[n];
}

// ---- double-buffered GEMM core: BM=128 BN=64, template BK ----
// ONE barrier per BK-iter: sync -> issue DMA for tile i+1 (alt buffer) ->
// compute tile i. SPLITS: 3 = aH*bH+aH*bL+aL*bH ; 2 = aH*bH+aL*bH ; 1 = aH*bH
template<int SPLITS, int BK>
__device__ __forceinline__ void gemm_core_db(
    const u16* __restrict__ Ah, const u16* __restrict__ Al, int lda,
    const u16* __restrict__ Bh, const u16* __restrict__ Bl, int K,
    int m0, int n0, f32x4_t (&acc)[4][2],
    u16* sAh, u16* sAl, u16* sBh, u16* sBl)
{
  constexpr int NH  = BK / 32;
  constexpr int ASZ = 128 * BK;
  constexpr int BSZ = 64 * BK;
  int tid = threadIdx.x;
  int lane = tid & 63, w = tid >> 6, quad = lane >> 4, l15 = lane & 15;
  int wm = w & 1, wn = w >> 1;
  int lrow = lane >> 2;
  int swzS = ((lane >> 2) & 3) ^ ((lane >> 4) & 3);
  int gkq  = ((lane & 3) ^ swzS) * 8;
  const u16* pA0 = Ah + (size_t)(m0 + w * 32 + lrow) * lda + gkq;
  const u16* pA1 = Ah + (size_t)(m0 + w * 32 + 16 + lrow) * lda + gkq;
  const u16* pL0 = (SPLITS >= 2) ? Al + (size_t)(m0 + w * 32 + lrow) * lda + gkq : nullptr;
  const u16* pL1 = (SPLITS >= 2) ? Al + (size_t)(m0 + w * 32 + 16 + lrow) * lda + gkq : nullptr;
  const u16* pB0 = Bh + (size_t)(n0 + w * 16 + lrow) * K + gkq;
  const u16* pBl = (SPLITS == 3) ? Bl + (size_t)(n0 + w * 16 + lrow) * K + gkq : nullptr;
  int pq = (quad ^ ((l15 & 3) ^ ((l15 >> 2) & 3))) * 8;
  const int NIT = K / BK;

  auto stage = [&](int it){
    int bi = it & 1, k0 = it * BK;
    u16* dA = sAh + bi * ASZ + w * 1024;
    u16* dB = sBh + bi * BSZ + w * 512;
#pragma unroll
    for (int hf = 0; hf < NH; hf++){
      gl2lds16(pA0 + k0 + hf * 32, dA + hf * 4096);
      gl2lds16(pA1 + k0 + hf * 32, dA + hf * 4096 + 512);
      if constexpr (SPLITS >= 2){
        u16* dAl = sAl + bi * ASZ + w * 1024;
        gl2lds16(pL0 + k0 + hf * 32, dAl + hf * 4096);
        gl2lds16(pL1 + k0 + hf * 32, dAl + hf * 4096 + 512);
      }
      gl2lds16(pB0 + k0 + hf * 32, dB + hf * 2048);
      if constexpr (SPLITS == 3){
        u16* dBl = sBl + bi * BSZ + w * 512;
        gl2lds16(pBl + k0 + hf * 32, dBl + hf * 2048);
      }
    }
  };

  stage(0);
  for (int it = 0; it < NIT; ++it){
    int bi = it & 1;
    __syncthreads();                 // drains tile-i DMA (issued one iter ago)
    if (it + 1 < NIT) stage(it + 1);
#pragma unroll
    for (int hf = 0; hf < NH; hf++){
      bf16x8_t aH[4], aL[4], bH[2], bL[2];
#pragma unroll
      for (int mi = 0; mi < 4; mi++){
        int ad = (wm * 64 + mi * 16 + l15) * 32 + pq + bi * ASZ + hf * 4096;
        aH[mi] = *(const bf16x8_t*)&sAh[ad];
        if constexpr (SPLITS >= 2) aL[mi] = *(const bf16x8_t*)&sAl[ad];
      }
#pragma unroll
      for (int ni = 0; ni < 2; ni++){
        int bd = (wn * 32 + ni * 16 + l15) * 32 + pq + bi * BSZ + hf * 2048;
        bH[ni] = *(const bf16x8_t*)&sBh[bd];
        if constexpr (SPLITS == 3) bL[ni] = *(const bf16x8_t*)&sBl[bd];
      }
#pragma unroll
      for (int mi = 0; mi < 4; mi++)
#pragma unroll
        for (int ni = 0; ni < 2; ni++){
          acc[mi][ni] = __builtin_amdgcn_mfma_f32_16x16x32_bf16(aH[mi], bH[ni], acc[mi][ni], 0, 0, 0);
          if constexpr (SPLITS == 3)
            acc[mi][ni] = __builtin_amdgcn_mfma_f32_16x16x32_bf16(aH[mi], bL[ni], acc[mi][ni], 0, 0, 0);
          if constexpr (SPLITS >= 2)
            acc[mi][ni] = __builtin_amdgcn_mfma_f32_16x16x32_bf16(aL[mi], bH[ni], acc[mi][ni], 0, 0, 0);
        }
    }
  }
}

// ---- prep pass 2: combined weights on the MATRIX pipe ----
// C[k][n] = sum_j Wf[k][j] * Wsec[j][n], split-3 MFMA (~f32 accuracy), written
// TRANSPOSED as Wout[n][k] bf16-hi (packed uint2 stores, gm0 4-aligned).
// grid (8, 16): side = y>>3 (0=Q, 1=K), n0=(y&7)*64, m0=x*128 over k=1024.
__global__ __launch_bounds__(256, 2) void combine_kernel(
    const u16* __restrict__ Wfh, const u16* __restrict__ Wfl,
    const u16* __restrict__ Wqth, const u16* __restrict__ Wqtl,
    const u16* __restrict__ Wkth, const u16* __restrict__ Wktl,
    u16* __restrict__ Wfqt, u16* __restrict__ Wfkt)
{
  __shared__ __align__(16) u16 sAh[2 * 4096], sAl[2 * 4096], sBh[2 * 2048], sBl[2 * 2048];
  int side = blockIdx.y >> 3;
  int m0 = blockIdx.x * 128, n0 = (blockIdx.y & 7) * 64;
  const u16* Bh = side ? Wkth : Wqth;
  const u16* Bl = side ? Wktl : Wqtl;
  u16* Outp = side ? Wfkt : Wfqt;

  f32x4_t acc[4][2];
#pragma unroll
  for (int i = 0; i < 4; i++)
#pragma unroll
    for (int j = 0; j < 2; j++)
#pragma unroll
      for (int r = 0; r < 4; r++) acc[i][j][r] = 0.f;
  gemm_core_db<3, 32>(Wfh, Wfl, 512, Bh, Bl, 512, m0, n0, acc, sAh, sAl, sBh, sBl);

  int lane = threadIdx.x & 63, w = threadIdx.x >> 6, quad = lane >> 4, l15 = lane & 15;
  int wm = w & 1, wn = w >> 1;
#pragma unroll
  for (int mi = 0; mi < 4; mi++)
#pragma unroll
    for (int ni = 0; ni < 2; ni++){
      int gn = n0 + wn * 32 + ni * 16 + l15;
      int gm0 = m0 + wm * 64 + mi * 16 + quad * 4;
      u16 hs[4];
#pragma unroll
      for (int r = 0; r < 4; r++) hs[r] = f2bf(acc[mi][ni][r]);
      *(uint2*)(Outp + (size_t)gn * 1024 + gm0) =
          make_uint2(hs[0] | ((unsigned)hs[1] << 16), hs[2] | ((unsigned)hs[3] << 16));
    }
}

// Q|K|V in one launch. grid (64, 24): side = y>>3 (0=Q,1=K,2=V), n0=(y&7)*64.
// Q,K: A = full X (lda 1024, K=1024), B = combined Wfq^T/Wfk^T.
// V:   A = expr half (lda 1024, K=512), B = Wv^T.
// 40 KB live LDS + 12 KB pad -> exactly 3 blocks/CU (grid 1536 = 3/CU exact).
__global__ __launch_bounds__(256, 3) void gemm_qkv_kernel(
    const u16* __restrict__ Xh, const u16* __restrict__ Xl,
    const u16* __restrict__ Wfqt, const u16* __restrict__ Wfkt, const u16* __restrict__ Wvth,
    const float* __restrict__ bfq, const float* __restrict__ bfk, const float* __restrict__ bv,
    u16* __restrict__ Q, u16* __restrict__ Kout, u16* __restrict__ Vt, float qsc)
{
  __shared__ __align__(16) u16 sAh[2 * 4096], sAl[2 * 4096], sBh[2 * 2048];
  __shared__ u16 sPad[6144];   // occupancy shaper: 53248 B -> 3 blocks/CU
  if (qsc < 0.f){ sPad[threadIdx.x] = 0; __syncthreads(); sAh[0] = sPad[0]; }

  int side = blockIdx.y >> 3;
  int m0 = blockIdx.x * 128, n0 = (blockIdx.y & 7) * 64;
  const u16* Ah = (side == 2) ? Xh + 512 : Xh;
  const u16* Al = (side == 2) ? Xl + 512 : Xl;
  int K = (side == 2) ? 512 : 1024;
  const u16* Bh = (side == 0) ? Wfqt : (side == 1) ? Wfkt : Wvth;
  const float* bias = (side == 0) ? bfq : (side == 1) ? bfk : bv;

  f32x4_t acc[4][2];
#pragma unroll
  for (int i = 0; i < 4; i++)
#pragma unroll
    for (int j = 0; j < 2; j++)
#pragma unroll
      for (int r = 0; r < 4; r++) acc[i][j][r] = 0.f;
  gemm_core_db<2, 32>(Ah, Al, 1024, Bh, nullptr, K, m0, n0, acc, sAh, sAl, sBh, nullptr);

  int lane = threadIdx.x & 63, w = threadIdx.x >> 6, quad = lane >> 4, l15 = lane & 15;
  int wm = w & 1, wn = w >> 1;
#pragma unroll
  for (int mi = 0; mi < 4; mi++)
#pragma unroll
    for (int ni = 0; ni < 2; ni++){
      int gn = n0 + wn * 32 + ni * 16 + l15;
      float bs = bias[gn];
      int gm0 = m0 + wm * 64 + mi * 16 + quad * 4;
#pragma unroll
      for (int r = 0; r < 4; r++){
        float v = acc[mi][ni][r] + bs;
        int gm = gm0 + r;
        if (side == 0){
          Q[(size_t)gm * 512 + gn] = f2bf(v * qsc);
        } else if (side == 1){
          Kout[(size_t)gm * 512 + gn] = f2bf(v);
        } else {
          int bb = gm >> 11, s = gm & 2047;
          int hh = gn >> 6, d = gn & 63;
          Vt[((size_t)((bb * 8 + hh) * 64 + d) << 11) + s] = f2bf(v);
        }
      }
    }
}

// out = O @ Wo + bo -> f32. grid (64, 8). 48 KB -> 2 blocks/CU exact.
__global__ __launch_bounds__(256, 2) void gemm_o_kernel(
    const u16* __restrict__ Oh, const u16* __restrict__ Woth,
    const float* __restrict__ bias, float* __restrict__ out)
{
  __shared__ __align__(16) u16 sAh[2 * 8192], sBh[2 * 4096];
  int m0 = blockIdx.x * 128, n0 = blockIdx.y * 64;
  f32x4_t acc[4][2];
#pragma unroll
  for (int i = 0; i < 4; i++)
#pragma unroll
    for (int j = 0; j < 2; j++)
#pragma unroll
      for (int r = 0; r < 4; r++) acc[i][j][r] = 0.f;
  gemm_core_db<1, 64>(Oh, nullptr, 512, Woth, nullptr, 512, m0, n0, acc, sAh, nullptr, sBh, nullptr);

  int lane = threadIdx.x & 63, w = threadIdx.x >> 6, quad = lane >> 4, l15 = lane & 15;
  int wm = w & 1, wn = w >> 1;
#pragma unroll
  for (int mi = 0; mi < 4; mi++)
#pragma unroll
    for (int ni = 0; ni < 2; ni++){
      int gn = n0 + wn * 32 + ni * 16 + l15;
      float bs = bias[gn];
      int gm0 = m0 + wm * 64 + mi * 16 + quad * 4;
#pragma unroll
      for (int r = 0; r < 4; r++)
        out[(size_t)(gm0 + r) * 512 + gn] = acc[mi][ni][r] + bs;
    }
}

// ---- flash attention: 4 waves x 16 q = 64 q/block, double-buffered K/V,
// ONE barrier per iter, XOR-swizzled sP. LDS = 16K + 16K + 8K = 40960 B exactly
// -> 4 blocks/CU x 4 waves = 16 waves/CU = 4/SIMD (VGPR capped at 128).
// Q pre-scaled by 0.125*log2(e); p = M*exp2(s*M); l = sum p; O = (sum p*V)/l.
__global__ __launch_bounds__(256, 4) void flash_kernel(
    const u16* __restrict__ Qh, const u16* __restrict__ Kh,
    const u16* __restrict__ Vt, const float* __restrict__ Mm,
    u16* __restrict__ Oh)
{
  __shared__ __align__(16) u16 sKh[2 * 4096], sVt[2 * 4096], sP[4096];
  int tid = threadIdx.x, lane = tid & 63, w = tid >> 6, quad = lane >> 4, l15 = lane & 15;
  int bh = blockIdx.y, b = bh >> 3, h = bh & 7;
  int q0 = blockIdx.x * 64;

  int qrow = q0 + w * 16 + l15;
  const u16* qp = Qh + ((size_t)(b * 2048 + qrow)) * 512 + h * 64 + quad * 8;
  bf16x8_t qH[2];
  qH[0] = *(const bf16x8_t*)qp;  qH[1] = *(const bf16x8_t*)(qp + 32);

  float lp[4] = {0.f, 0.f, 0.f, 0.f};
  f32x4_t Oacc[4];
#pragma unroll
  for (int ni = 0; ni < 4; ni++)
#pragma unroll
    for (int r = 0; r < 4; r++) Oacc[ni][r] = 0.f;

  // staging: wave w stages rows [w*16, w*16+16); granule g holds cols (g^(row&7))*8..
  int srow = lane >> 3;
  int gc = ((lane & 7) ^ srow) * 8;
  const u16* gK = Kh + ((size_t)(b * 2048 + w * 16 + srow)) * 512 + h * 64 + gc;
  const u16* gV = Vt + ((size_t)(bh * 64 + w * 16 + srow)) * 2048 + gc;

  auto stage = [&](int it){
    int bi = it & 1, k0 = it * 64;
    u16* dK = sKh + bi * 4096 + w * 1024;
    u16* dV = sVt + bi * 4096 + w * 1024;
    gl2lds16(gK + (size_t)k0 * 512,       dK);
    gl2lds16(gK + (size_t)(k0 + 8) * 512, dK + 512);
    gl2lds16(gV + k0,                     dV);
    gl2lds16(gV + 8 * 2048 + k0,          dV + 512);
  };

  const float* Mbase = Mm + (size_t)b * 2048 * 2048 + (size_t)(q0 + w * 16) * 2048;
  stage(0);

  // M for tile 0
  float Mc[4][4];
#pragma unroll
  for (int ni = 0; ni < 4; ni++)
#pragma unroll
    for (int r = 0; r < 4; r++)
      Mc[ni][r] = Mbase[(size_t)(quad * 4 + r) * 2048 + ni * 16 + l15];

  int sw7 = l15 & 7;
  for (int it = 0; it < 32; ++it){
    int bi = it & 1;
    const u16* cK = sKh + bi * 4096;
    const u16* cV = sVt + bi * 4096;
    __syncthreads();                 // drains tile-i DMA (issued one iter ago)
    bool hasNext = (it + 1) < 32;
    if (hasNext) stage(it + 1);

    // prefetch next tile's M (consumed next iteration)
    float Mn[4][4];
    if (hasNext){
      int kn = (it + 1) * 64;
#pragma unroll
      for (int ni = 0; ni < 4; ni++)
#pragma unroll
        for (int r = 0; r < 4; r++)
          Mn[ni][r] = Mbase[(size_t)(quad * 4 + r) * 2048 + kn + ni * 16 + l15];
    }

    // scores = Q . K^T (bf16)
    f32x4_t S[4];
#pragma unroll
    for (int ni = 0; ni < 4; ni++)
#pragma unroll
      for (int r = 0; r < 4; r++) S[ni][r] = 0.f;
#pragma unroll
    for (int ni = 0; ni < 4; ni++){
      int kb = (ni * 16 + l15) * 64;
#pragma unroll
      for (int ds = 0; ds < 2; ds++){
        bf16x8_t kf = *(const bf16x8_t*)&cK[kb + (((ds * 4 + quad) ^ sw7)) * 8];
        S[ni] = __builtin_amdgcn_mfma_f32_16x16x32_bf16(qH[ds], kf, S[ni], 0, 0, 0);
      }
    }

    // p = M*exp2(s*M); per-lane l; truncation-store bf16 P (wave-private, swizzled)
#pragma unroll
    for (int ni = 0; ni < 4; ni++)
#pragma unroll
      for (int r = 0; r < 4; r++){
        float m = Mc[ni][r];
        float p = m * __builtin_amdgcn_exp2f(S[ni][r] * m);
        lp[r] += p;
        int row = quad * 4 + r;
        int colg = ni * 2 + (l15 >> 3);
        sP[w * 1024 + row * 64 + ((colg ^ (row & 7)) << 3) + (l15 & 7)] = hi16(p);
      }

    // O += P @ V (wave-private sP rows; lgkmcnt only, no barrier)
#pragma unroll
    for (int ds = 0; ds < 2; ds++){
      bf16x8_t pf = *(const bf16x8_t*)&sP[w * 1024 + l15 * 64 + (((ds * 4 + quad) ^ sw7) << 3)];
#pragma unroll
      for (int ni = 0; ni < 4; ni++){
        bf16x8_t vf = *(const bf16x8_t*)&cV[(ni * 16 + l15) * 64 + (((ds * 4 + quad) ^ sw7)) * 8];
        Oacc[ni] = __builtin_amdgcn_mfma_f32_16x16x32_bf16(pf, vf, Oacc[ni], 0, 0, 0);
      }
    }

    if (hasNext){
#pragma unroll
      for (int ni = 0; ni < 4; ni++)
#pragma unroll
        for (int r = 0; r < 4; r++) Mc[ni][r] = Mn[ni][r];
    }
  }

#pragma unroll
  for (int r = 0; r < 4; r++){
#pragma unroll
    for (int off = 1; off < 16; off <<= 1)
      lp[r] += __shfl_xor(lp[r], off);
  }

#pragma unroll
  for (int r = 0; r < 4; r++){
    float inv = 1.0f / lp[r];
    int q = q0 + w * 16 + quad * 4 + r;
    size_t rb = ((size_t)(b * 2048 + q)) * 512 + h * 64;
#pragma unroll
    for (int ni = 0; ni < 4; ni++)
      Oh[rb + ni * 16 + l15] = f2bf(Oacc[ni][r] * inv);
  }
}

extern "C" void kernel_launch(void* const* d_in, const int* in_sizes, int n_in,
                              void* d_out, int out_size, void* d_ws, size_t ws_size,
                              hipStream_t stream)
{
  const float* gene = (const float*)d_in[0];
  const float* expr = (const float*)d_in[1];
  const float* Mm   = (const float*)d_in[2];
  const float* Wf   = (const float*)d_in[3];
  const float* bfv  = (const float*)d_in[4];
  const float* Wq   = (const float*)d_in[5];
  const float* bq   = (const float*)d_in[6];
  const float* Wk   = (const float*)d_in[7];
  const float* bk   = (const float*)d_in[8];
  const float* Wv   = (const float*)d_in[9];
  const float* bv   = (const float*)d_in[10];
  const float* Wo   = (const float*)d_in[11];
  const float* bo   = (const float*)d_in[12];
  float* out = (float*)d_out;

  char* ws = (char*)d_ws;
  size_t off = 0;
  auto alloc = [&](size_t bytes) -> void* {
    void* p = (void*)(ws + off);
    off += (bytes + 255) & ~(size_t)255;
    return p;
  };
  u16* Xh    = (u16*)alloc(8192ull * 1024 * 2);
  u16* Xl    = (u16*)alloc(8192ull * 1024 * 2);
  u16* Wfh   = (u16*)alloc(1024ull * 512 * 2);
  u16* Wfl   = (u16*)alloc(1024ull * 512 * 2);
  u16* Wqth  = (u16*)alloc(512ull * 512 * 2);
  u16* Wqtl  = (u16*)alloc(512ull * 512 * 2);
  u16* Wkth  = (u16*)alloc(512ull * 512 * 2);
  u16* Wktl  = (u16*)alloc(512ull * 512 * 2);
  u16* Wvth  = (u16*)alloc(512ull * 512 * 2);
  u16* Woth  = (u16*)alloc(512ull * 512 * 2);
  u16* Wfqt  = (u16*)alloc(512ull * 1024 * 2);
  u16* Wfkt  = (u16*)alloc(512ull * 1024 * 2);
  float* bfq = (float*)alloc(512 * 4);
  float* bfk = (float*)alloc(512 * 4);
  u16* Qh    = (u16*)alloc(8192ull * 512 * 2);
  u16* Kh    = (u16*)alloc(8192ull * 512 * 2);
  u16* Vt    = (u16*)alloc(8192ull * 512 * 2);
  u16* Oh = Xh;   // X dead after QKV; attention output aliases it

  const float QSC = 0.1803368801f;   // 0.125 * log2(e) — folded into Q, exp via exp2

  prep_kernel<<<8964, 256, 0, stream>>>(gene, expr, Wf, Wq, Wk, Wv, Wo, bfv, bq, bk,
                                        Xh, Xl, Wfh, Wfl, Wqth, Wqtl, Wkth, Wktl,
                                        Wvth, Woth, bfq, bfk);
  combine_kernel<<<dim3(8, 16), 256, 0, stream>>>(Wfh, Wfl, Wqth, Wqtl, Wkth, Wktl,
                                                  Wfqt, Wfkt);
  gemm_qkv_kernel<<<dim3(64, 24), 256, 0, stream>>>(Xh, Xl, Wfqt, Wfkt, Wvth,
                                                    bfq, bfk, bv, Qh, Kh, Vt, QSC);
  flash_kernel<<<dim3(32, 32), 256, 0, stream>>>(Qh, Kh, Vt, Mm, Oh);
  gemm_o_kernel<<<dim3(64, 8), 256, 0, stream>>>(Oh, Woth, bo, out);

  (void)in_sizes; (void)n_in; (void)out_size; (void)ws_size;
}